// Round 3
// baseline (195.952 us; speedup 1.0000x reference)
//
#include <hip/hip_runtime.h>
#include <hip/hip_cooperative_groups.h>
#include <math.h>

namespace cg = cooperative_groups;

// ParametricEQ: 5-section cascaded biquad over (32, 131072).
// Single 10-state linear recurrence z' = A z + b x.
//   K1 setup (32 blocks): RBJ coeffs (fp64) + P_m = A^(32*2^m), m=0..11 (fp64->fp32)
//   K2 cooperative main (2048 blocks = 1 wave each = one 64-chunk span):
//     phase 1: x -> regs, zero-state cascade per 32-sample chunk -> v (regs),
//              in-wave KS scan (P_0..P_5) -> span total -> Tspan
//     grid.sync()
//     phase 2: in-wave KS over 64 span totals (P_6..P_11) -> this span's seed,
//              seed' = P0^lane * seed (6 conditional matvecs), entering state =
//              escan + seed', exact cascade from entering state -> y.

#define NB 32
#define LCH 32
#define T_LEN 131072
#define C_CH (T_LEN / LCH)     // 4096 chunks per batch
#define SPANS (C_CH / 64)      // 64 spans per batch
#define NPOW 12

__constant__ double c_lo[15] = {-12.0,   20.0, 0.1,
                                -12.0,   20.0, 0.1,
                                -12.0,  200.0, 0.1,
                                -12.0, 2000.0, 0.1,
                                -12.0, 4000.0, 0.1};
__constant__ double c_hi[15] = { 12.0,  2000.0, 10.0,
                                 12.0,   200.0, 10.0,
                                 12.0,  2000.0, 10.0,
                                 12.0, 12000.0, 10.0,
                                 12.0, 16000.0, 10.0};

// ---------------- K1: coeffs + cascade matrix powers (per-batch block) -------
__global__ __launch_bounds__(128)
void eq_setup(const float* __restrict__ cp, float* __restrict__ sos_out,
              float* __restrict__ powers)
{
    int b = blockIdx.x;
    int t = threadIdx.x;
    __shared__ float  sc[5][5];            // b0,b1,b2,a1,a2 (fp32-rounded)
    __shared__ double Abuf[2][10][10];

    if (t < 5) {
        int k = t;
        double p[3];
#pragma unroll
        for (int j = 0; j < 3; ++j) {
            int i = k * 3 + j;
            double pv = (double)cp[b * 15 + i];
            p[j] = c_lo[i] + pv * (c_hi[i] - c_lo[i]);
        }
        double A     = exp(p[0] * (M_LN10 / 40.0));
        double w0    = 2.0 * M_PI * p[1] / 44100.0;
        double alpha = sin(w0) / (2.0 * p[2]);
        double cw    = cos(w0);
        double sA    = sqrt(A);
        double b0, b1, b2, a0, a1, a2;
        if (k == 0) {            // low shelf
            b0 =     A * ((A + 1) - (A - 1) * cw + 2 * sA * alpha);
            b1 = 2 * A * ((A - 1) - (A + 1) * cw);
            b2 =     A * ((A + 1) - (A - 1) * cw - 2 * sA * alpha);
            a0 =          (A + 1) + (A - 1) * cw + 2 * sA * alpha;
            a1 =    -2 * ((A - 1) + (A + 1) * cw);
            a2 =          (A + 1) + (A - 1) * cw - 2 * sA * alpha;
        } else if (k == 4) {     // high shelf
            b0 =     A * ((A + 1) + (A - 1) * cw + 2 * sA * alpha);
            b1 = -2 * A * ((A - 1) + (A + 1) * cw);
            b2 =     A * ((A + 1) + (A - 1) * cw - 2 * sA * alpha);
            a0 =          (A + 1) - (A - 1) * cw + 2 * sA * alpha;
            a1 =     2 * ((A - 1) - (A + 1) * cw);
            a2 =          (A + 1) - (A - 1) * cw - 2 * sA * alpha;
        } else {                 // peaking
            b0 = 1.0 + alpha * A;
            b1 = -2.0 * cw;
            b2 = 1.0 - alpha * A;
            a0 = 1.0 + alpha / A;
            a1 = -2.0 * cw;
            a2 = 1.0 - alpha / A;
        }
        double inv = 1.0 / a0;
        float fb0 = (float)(b0 * inv), fb1 = (float)(b1 * inv), fb2 = (float)(b2 * inv);
        float fa1 = (float)(a1 * inv), fa2 = (float)(a2 * inv);
        float* o = sos_out + (size_t)(b * 5 + k) * 6;
        o[0] = fb0; o[1] = fb1; o[2] = fb2; o[3] = 1.0f; o[4] = fa1; o[5] = fa2;
        sc[k][0] = fb0; sc[k][1] = fb1; sc[k][2] = fb2; sc[k][3] = fa1; sc[k][4] = fa2;
    }
    __syncthreads();

    // A (10x10): column i = one-sample cascade update of basis e_i with x=0.
    if (t < 10) {
        double z[10];
#pragma unroll
        for (int i = 0; i < 10; ++i) z[i] = 0.0;
        z[t] = 1.0;
        double s = 0.0;
        double zn[10];
#pragma unroll
        for (int k = 0; k < 5; ++k) {
            double b0 = sc[k][0], b1 = sc[k][1], b2 = sc[k][2];
            double a1 = sc[k][3], a2 = sc[k][4];
            double y = b0 * s + z[2 * k];
            zn[2 * k]     = b1 * s - a1 * y + z[2 * k + 1];
            zn[2 * k + 1] = b2 * s - a2 * y;
            s = y;
        }
#pragma unroll
        for (int r = 0; r < 10; ++r) Abuf[0][r][t] = zn[r];
    }
    __syncthreads();

    int r = t / 10, cc = t % 10;
    int cur = 0;
    for (int sq = 0; sq < 16; ++sq) {
        double acc = 0.0;
        if (t < 100) {
#pragma unroll
            for (int j = 0; j < 10; ++j) acc += Abuf[cur][r][j] * Abuf[cur][j][cc];
        }
        __syncthreads();
        if (t < 100) Abuf[cur ^ 1][r][cc] = acc;
        __syncthreads();
        cur ^= 1;
        if (sq >= 4 && t < 100) {
            int m = sq - 4;   // sq=4 -> A^32 = P_0
            powers[((size_t)b * NPOW + m) * 100 + t] = (float)Abuf[cur][r][cc];
        }
    }
}

// ---- in-wave Kogge-Stone affine scan with constant multipliers Pb[j] -------
__device__ __forceinline__ void ks_scan(float sv[10], const float* __restrict__ Pb, int lane)
{
#pragma unroll
    for (int j = 0; j < 6; ++j) {
        const float* P = Pb + j * 100;
        float u[10];
#pragma unroll
        for (int i = 0; i < 10; ++i) u[i] = __shfl_up(sv[i], 1 << j);
        if (lane >= (1 << j)) {
            float ns[10];
#pragma unroll
            for (int rr = 0; rr < 10; ++rr) {
                float acc = sv[rr];
#pragma unroll
                for (int c2 = 0; c2 < 10; ++c2) acc = fmaf(P[rr * 10 + c2], u[c2], acc);
                ns[rr] = acc;
            }
#pragma unroll
            for (int i = 0; i < 10; ++i) sv[i] = ns[i];
        }
    }
}

// ---------------- K2: cooperative main ----------------
__global__ __launch_bounds__(64)
void eq_main(const float* __restrict__ x, const float* __restrict__ sos,
             const float* __restrict__ powers, float* __restrict__ Tspan,
             float* __restrict__ y)
{
    cg::grid_group grid = cg::this_grid();
    int blk = blockIdx.x;
    int b = blk >> 6, sp = blk & 63;
    int l = threadIdx.x;

    const float* s5 = sos + (size_t)(b * 5) * 6;
    float cb0[5], cb1[5], cb2[5], ca1[5], ca2[5];
#pragma unroll
    for (int k = 0; k < 5; ++k) {
        cb0[k] = s5[k * 6 + 0]; cb1[k] = s5[k * 6 + 1]; cb2[k] = s5[k * 6 + 2];
        ca1[k] = s5[k * 6 + 4]; ca2[k] = s5[k * 6 + 5];
    }

    // ---- load this chunk's 32 samples into registers ----
    int c = sp * 64 + l;
    const float* xp = x + (size_t)b * T_LEN + (size_t)c * LCH;
    float xr[LCH];
#pragma unroll
    for (int t0 = 0; t0 < LCH; t0 += 4) {
        float4 xv = *reinterpret_cast<const float4*>(xp + t0);
        xr[t0] = xv.x; xr[t0 + 1] = xv.y; xr[t0 + 2] = xv.z; xr[t0 + 3] = xv.w;
    }

    // ---- phase 1: zero-state cascade -> chunk end state ----
    float z1[5] = {0, 0, 0, 0, 0}, z2[5] = {0, 0, 0, 0, 0};
#pragma unroll
    for (int j = 0; j < LCH; ++j) {
        float s = xr[j];
#pragma unroll
        for (int k = 0; k < 5; ++k) {
            float yk = fmaf(cb0[k], s, z1[k]);
            float u  = fmaf(cb1[k], s, z2[k]);
            z1[k] = fmaf(-ca1[k], yk, u);
            z2[k] = fmaf(-ca2[k], yk, cb2[k] * s);
            s = yk;
        }
    }
    float sv[10];
#pragma unroll
    for (int k = 0; k < 5; ++k) { sv[2 * k] = z1[k]; sv[2 * k + 1] = z2[k]; }

    const float* Pb = powers + (size_t)b * NPOW * 100;
    ks_scan(sv, Pb, l);                       // inclusive chunk scan in span

    float es[10];                             // exclusive = entering (from span start)
#pragma unroll
    for (int i = 0; i < 10; ++i) es[i] = __shfl_up(sv[i], 1);
    if (l == 0) {
#pragma unroll
        for (int i = 0; i < 10; ++i) es[i] = 0.0f;
    }

    if (l == 63) {
#pragma unroll
        for (int i = 0; i < 10; ++i) Tspan[(size_t)(b * 10 + i) * 64 + sp] = sv[i];
    }

    grid.sync();

    // ---- phase 2: span seed scan (redundant per block, in-wave) ----
    float tv[10];
#pragma unroll
    for (int i = 0; i < 10; ++i) tv[i] = Tspan[(size_t)(b * 10 + i) * 64 + l];
    ks_scan(tv, Pb + 6 * 100, l);             // multipliers P_6..P_11

    float sd[10];                             // seed entering this span
#pragma unroll
    for (int i = 0; i < 10; ++i) sd[i] = __shfl(tv[i], (sp - 1) & 63);
    if (sp == 0) {
#pragma unroll
        for (int i = 0; i < 10; ++i) sd[i] = 0.0f;
    }

    // sd = P0^l * sd  (conditional matvec per bit of lane index)
#pragma unroll
    for (int m = 0; m < 6; ++m) {
        const float* P = Pb + m * 100;
        float ns[10];
#pragma unroll
        for (int rr = 0; rr < 10; ++rr) {
            float acc = 0.0f;
#pragma unroll
            for (int c2 = 0; c2 < 10; ++c2) acc = fmaf(P[rr * 10 + c2], sd[c2], acc);
            ns[rr] = acc;
        }
        bool on = (l >> m) & 1;
#pragma unroll
        for (int i = 0; i < 10; ++i) sd[i] = on ? ns[i] : sd[i];
    }

    // exact entering state of chunk c
#pragma unroll
    for (int k = 0; k < 5; ++k) {
        z1[k] = es[2 * k]     + sd[2 * k];
        z2[k] = es[2 * k + 1] + sd[2 * k + 1];
    }

    // ---- final cascade from true state -> y ----
    float* yp = y + (size_t)b * T_LEN + (size_t)c * LCH;
#pragma unroll
    for (int t0 = 0; t0 < LCH; t0 += 4) {
        float o4[4];
#pragma unroll
        for (int j = 0; j < 4; ++j) {
            float s = xr[t0 + j];
#pragma unroll
            for (int k = 0; k < 5; ++k) {
                float yk = fmaf(cb0[k], s, z1[k]);
                float u  = fmaf(cb1[k], s, z2[k]);
                z1[k] = fmaf(-ca1[k], yk, u);
                z2[k] = fmaf(-ca2[k], yk, cb2[k] * s);
                s = yk;
            }
            o4[j] = s;
        }
        *reinterpret_cast<float4*>(yp + t0) = make_float4(o4[0], o4[1], o4[2], o4[3]);
    }
}

extern "C" void kernel_launch(void* const* d_in, const int* in_sizes, int n_in,
                              void* d_out, int out_size, void* d_ws, size_t ws_size,
                              hipStream_t stream)
{
    const float* x  = (const float*)d_in[0];
    const float* cp = (const float*)d_in[1];
    float* out = (float*)d_out;
    float* sos = out + (size_t)NB * T_LEN;          // sos tail of d_out

    float* powers = (float*)d_ws;                   // NB*NPOW*100 floats
    float* Tspan  = powers + (size_t)NB * NPOW * 100;  // NB*10*64 floats

    eq_setup<<<dim3(NB), dim3(128), 0, stream>>>(cp, sos, powers);

    const float* xs = x; const float* ss = sos; const float* ps = powers;
    float* ts = Tspan; float* ys = out;
    void* kargs[] = { (void*)&xs, (void*)&ss, (void*)&ps, (void*)&ts, (void*)&ys };
    hipLaunchCooperativeKernel((void*)eq_main, dim3(NB * SPANS), dim3(64),
                               kargs, 0, stream);
}

// Round 4
// 58.122 us; speedup vs baseline: 3.3714x; 3.3714x over previous
//
#include <hip/hip_runtime.h>
#include <math.h>

// ParametricEQ: 5-section cascaded biquad over (32, 131072).
// Single 10-state linear recurrence z' = A z + b x, two launches:
//   K1 setup: RBJ coeffs (fp64) + P_m = A^(32*2^m) m=0..11; zero publish flags.
//   K2 main (512 blocks x 256 thr; block = 256 chunks x 32 samples = 8192 samples):
//     x->regs, zero-state cascade -> chunk states; in-wave KS (P_0..P_5);
//     LDS combine of 4 wave totals (P_6) -> block aggregate; publish (release);
//     wait all 16 sibling flags (acquire); in-wave KS over 16 aggregates
//     (P_8..P_11) -> block seed; conditional matvecs -> exact chunk entering
//     state; final cascade -> y.  No grid.sync, x read once from HBM.

#define NB 32
#define LCH 32
#define T_LEN 131072
#define CPB 256                 // chunks per block
#define SPB 16                  // blocks (spans) per batch
#define NPOW 12

__constant__ double c_lo[15] = {-12.0,   20.0, 0.1,
                                -12.0,   20.0, 0.1,
                                -12.0,  200.0, 0.1,
                                -12.0, 2000.0, 0.1,
                                -12.0, 4000.0, 0.1};
__constant__ double c_hi[15] = { 12.0,  2000.0, 10.0,
                                 12.0,   200.0, 10.0,
                                 12.0,  2000.0, 10.0,
                                 12.0, 12000.0, 10.0,
                                 12.0, 16000.0, 10.0};

// ---------------- K1: coeffs + cascade matrix powers + flag clear -----------
__global__ __launch_bounds__(128)
void eq_setup(const float* __restrict__ cp, float* __restrict__ sos_out,
              float* __restrict__ powers, unsigned int* __restrict__ flags)
{
    int b = blockIdx.x;
    int t = threadIdx.x;
    __shared__ float  sc[5][5];
    __shared__ double Abuf[2][10][10];

    if (t < SPB) flags[b * SPB + t] = 0u;   // clear publish flags (pre-main)

    if (t < 5) {
        int k = t;
        double p[3];
#pragma unroll
        for (int j = 0; j < 3; ++j) {
            int i = k * 3 + j;
            double pv = (double)cp[b * 15 + i];
            p[j] = c_lo[i] + pv * (c_hi[i] - c_lo[i]);
        }
        double A     = exp(p[0] * (M_LN10 / 40.0));
        double w0    = 2.0 * M_PI * p[1] / 44100.0;
        double alpha = sin(w0) / (2.0 * p[2]);
        double cw    = cos(w0);
        double sA    = sqrt(A);
        double b0, b1, b2, a0, a1, a2;
        if (k == 0) {            // low shelf
            b0 =     A * ((A + 1) - (A - 1) * cw + 2 * sA * alpha);
            b1 = 2 * A * ((A - 1) - (A + 1) * cw);
            b2 =     A * ((A + 1) - (A - 1) * cw - 2 * sA * alpha);
            a0 =          (A + 1) + (A - 1) * cw + 2 * sA * alpha;
            a1 =    -2 * ((A - 1) + (A + 1) * cw);
            a2 =          (A + 1) + (A - 1) * cw - 2 * sA * alpha;
        } else if (k == 4) {     // high shelf
            b0 =     A * ((A + 1) + (A - 1) * cw + 2 * sA * alpha);
            b1 = -2 * A * ((A - 1) + (A + 1) * cw);
            b2 =     A * ((A + 1) + (A - 1) * cw - 2 * sA * alpha);
            a0 =          (A + 1) - (A - 1) * cw + 2 * sA * alpha;
            a1 =     2 * ((A - 1) - (A + 1) * cw);
            a2 =          (A + 1) - (A - 1) * cw - 2 * sA * alpha;
        } else {                 // peaking
            b0 = 1.0 + alpha * A;
            b1 = -2.0 * cw;
            b2 = 1.0 - alpha * A;
            a0 = 1.0 + alpha / A;
            a1 = -2.0 * cw;
            a2 = 1.0 - alpha / A;
        }
        double inv = 1.0 / a0;
        float fb0 = (float)(b0 * inv), fb1 = (float)(b1 * inv), fb2 = (float)(b2 * inv);
        float fa1 = (float)(a1 * inv), fa2 = (float)(a2 * inv);
        float* o = sos_out + (size_t)(b * 5 + k) * 6;
        o[0] = fb0; o[1] = fb1; o[2] = fb2; o[3] = 1.0f; o[4] = fa1; o[5] = fa2;
        sc[k][0] = fb0; sc[k][1] = fb1; sc[k][2] = fb2; sc[k][3] = fa1; sc[k][4] = fa2;
    }
    __syncthreads();

    // A (10x10): column i = one-sample cascade update of basis e_i with x=0.
    if (t < 10) {
        double z[10];
#pragma unroll
        for (int i = 0; i < 10; ++i) z[i] = 0.0;
        z[t] = 1.0;
        double s = 0.0;
        double zn[10];
#pragma unroll
        for (int k = 0; k < 5; ++k) {
            double b0 = sc[k][0], b1 = sc[k][1], b2 = sc[k][2];
            double a1 = sc[k][3], a2 = sc[k][4];
            double y = b0 * s + z[2 * k];
            zn[2 * k]     = b1 * s - a1 * y + z[2 * k + 1];
            zn[2 * k + 1] = b2 * s - a2 * y;
            s = y;
        }
#pragma unroll
        for (int r = 0; r < 10; ++r) Abuf[0][r][t] = zn[r];
    }
    __syncthreads();

    int r = t / 10, cc = t % 10;
    int cur = 0;
    for (int sq = 0; sq < 16; ++sq) {
        double acc = 0.0;
        if (t < 100) {
#pragma unroll
            for (int j = 0; j < 10; ++j) acc += Abuf[cur][r][j] * Abuf[cur][j][cc];
        }
        __syncthreads();
        if (t < 100) Abuf[cur ^ 1][r][cc] = acc;
        __syncthreads();
        cur ^= 1;
        if (sq >= 4 && t < 100) {
            int m = sq - 4;   // sq=4 -> A^32 = P_0
            powers[((size_t)b * NPOW + m) * 100 + t] = (float)Abuf[cur][r][cc];
        }
    }
}

// ---- matvec helper: v = P * v ----
__device__ __forceinline__ void matvec(const float* __restrict__ P, float v[10])
{
    float ns[10];
#pragma unroll
    for (int rr = 0; rr < 10; ++rr) {
        float acc = 0.0f;
#pragma unroll
        for (int c2 = 0; c2 < 10; ++c2) acc = fmaf(P[rr * 10 + c2], v[c2], acc);
        ns[rr] = acc;
    }
#pragma unroll
    for (int i = 0; i < 10; ++i) v[i] = ns[i];
}

// ---------------- K2: main ----------------
__global__ __launch_bounds__(256, 4)
void eq_main(const float* __restrict__ x, const float* __restrict__ sos,
             const float* __restrict__ powers, float* __restrict__ agg,
             unsigned int* __restrict__ flags, float* __restrict__ y)
{
    int blk = blockIdx.x;
    int b = blk >> 4, sp = blk & (SPB - 1);
    int tid = threadIdx.x;
    int w = tid >> 6, lw = tid & 63;

    __shared__ float wt[4][10];    // wave totals
    __shared__ float Sseed[10];    // block entering state (global seed)

    const float* s5 = sos + (size_t)(b * 5) * 6;
    float cb0[5], cb1[5], cb2[5], ca1[5], ca2[5];
#pragma unroll
    for (int k = 0; k < 5; ++k) {
        cb0[k] = s5[k * 6 + 0]; cb1[k] = s5[k * 6 + 1]; cb2[k] = s5[k * 6 + 2];
        ca1[k] = s5[k * 6 + 4]; ca2[k] = s5[k * 6 + 5];
    }

    // ---- load 32 samples to registers ----
    int c = sp * CPB + tid;                       // chunk index in batch
    const float* xp = x + (size_t)b * T_LEN + (size_t)c * LCH;
    float xr[LCH];
#pragma unroll
    for (int t0 = 0; t0 < LCH; t0 += 4) {
        float4 xv = *reinterpret_cast<const float4*>(xp + t0);
        xr[t0] = xv.x; xr[t0 + 1] = xv.y; xr[t0 + 2] = xv.z; xr[t0 + 3] = xv.w;
    }

    // ---- zero-state cascade -> chunk end state ----
    float z1[5] = {0, 0, 0, 0, 0}, z2[5] = {0, 0, 0, 0, 0};
#pragma unroll
    for (int j = 0; j < LCH; ++j) {
        float s = xr[j];
#pragma unroll
        for (int k = 0; k < 5; ++k) {
            float yk = fmaf(cb0[k], s, z1[k]);
            float u  = fmaf(cb1[k], s, z2[k]);
            z1[k] = fmaf(-ca1[k], yk, u);
            z2[k] = fmaf(-ca2[k], yk, cb2[k] * s);
            s = yk;
        }
    }
    float sv[10];
#pragma unroll
    for (int k = 0; k < 5; ++k) { sv[2 * k] = z1[k]; sv[2 * k + 1] = z2[k]; }

    // ---- in-wave KS scan over 64 chunks (multipliers P_0..P_5) ----
    const float* Pb = powers + (size_t)b * NPOW * 100;
#pragma unroll
    for (int j = 0; j < 6; ++j) {
        const float* P = Pb + j * 100;
        float u[10];
#pragma unroll
        for (int i = 0; i < 10; ++i) u[i] = __shfl_up(sv[i], 1 << j);
        if (lw >= (1 << j)) {
            float ns[10];
#pragma unroll
            for (int rr = 0; rr < 10; ++rr) {
                float acc = sv[rr];
#pragma unroll
                for (int c2 = 0; c2 < 10; ++c2) acc = fmaf(P[rr * 10 + c2], u[c2], acc);
                ns[rr] = acc;
            }
#pragma unroll
            for (int i = 0; i < 10; ++i) sv[i] = ns[i];
        }
    }
    // exclusive in-wave prefix
    float es[10];
#pragma unroll
    for (int i = 0; i < 10; ++i) es[i] = __shfl_up(sv[i], 1);
    if (lw == 0) {
#pragma unroll
        for (int i = 0; i < 10; ++i) es[i] = 0.0f;
    }
    if (lw == 63) {
#pragma unroll
        for (int i = 0; i < 10; ++i) wt[w][i] = sv[i];
    }
    __syncthreads();

    // ---- block aggregate (thread 0): E = P6*E + wt[j], publish ----
    if (tid == 0) {
        float E[10];
#pragma unroll
        for (int i = 0; i < 10; ++i) E[i] = wt[0][i];
#pragma unroll
        for (int j = 1; j < 4; ++j) {
            matvec(Pb + 6 * 100, E);
#pragma unroll
            for (int i = 0; i < 10; ++i) E[i] += wt[j][i];
        }
        float* ap = agg + (size_t)(b * SPB + sp) * 10;
#pragma unroll
        for (int i = 0; i < 10; ++i)
            __hip_atomic_store(&ap[i], E[i], __ATOMIC_RELAXED, __HIP_MEMORY_SCOPE_AGENT);
        __hip_atomic_store(&flags[b * SPB + sp], 1u, __ATOMIC_RELEASE,
                           __HIP_MEMORY_SCOPE_AGENT);
    }

    // ---- wave 0: wait all 16 sibling aggregates, KS over 16 (P_8..P_11) ----
    if (w == 0) {
        float tv[10];
#pragma unroll
        for (int i = 0; i < 10; ++i) tv[i] = 0.0f;
        if (lw < SPB) {
            while (__hip_atomic_load(&flags[b * SPB + lw], __ATOMIC_ACQUIRE,
                                     __HIP_MEMORY_SCOPE_AGENT) == 0u) {
                __builtin_amdgcn_s_sleep(1);
            }
            const float* ap = agg + (size_t)(b * SPB + lw) * 10;
#pragma unroll
            for (int i = 0; i < 10; ++i)
                tv[i] = __hip_atomic_load(&ap[i], __ATOMIC_RELAXED,
                                          __HIP_MEMORY_SCOPE_AGENT);
        }
#pragma unroll
        for (int j = 0; j < 4; ++j) {
            const float* P = Pb + (8 + j) * 100;
            float u[10];
#pragma unroll
            for (int i = 0; i < 10; ++i) u[i] = __shfl_up(tv[i], 1 << j);
            if (lw >= (1 << j) && lw < SPB) {
                float ns[10];
#pragma unroll
                for (int rr = 0; rr < 10; ++rr) {
                    float acc = tv[rr];
#pragma unroll
                    for (int c2 = 0; c2 < 10; ++c2) acc = fmaf(P[rr * 10 + c2], u[c2], acc);
                    ns[rr] = acc;
                }
#pragma unroll
                for (int i = 0; i < 10; ++i) tv[i] = ns[i];
            }
        }
        // exclusive prefix for this block = inclusive at lane sp-1 (0 if sp==0)
        float sd[10];
#pragma unroll
        for (int i = 0; i < 10; ++i) sd[i] = __shfl(tv[i], (sp - 1) & 63);
        if (sp == 0) {
#pragma unroll
            for (int i = 0; i < 10; ++i) sd[i] = 0.0f;
        }
        if (lw == 0) {
#pragma unroll
            for (int i = 0; i < 10; ++i) Sseed[i] = sd[i];
        }
    }
    __syncthreads();

    // ---- exact entering state for this chunk ----
    // F_w = A^(w*2048) * S + E_w ; entering = A^(lw*32) * F_w + es
    float F[10];
#pragma unroll
    for (int i = 0; i < 10; ++i) F[i] = Sseed[i];
    if (w & 1) matvec(Pb + 6 * 100, F);   // P_6 = A^2048
    if (w & 2) matvec(Pb + 7 * 100, F);   // P_7 = A^4096
    // E_w = in-block zero-state prefix of waves < w
    {
        float Ew[10];
#pragma unroll
        for (int i = 0; i < 10; ++i) Ew[i] = 0.0f;
        for (int j = 0; j < w; ++j) {
            matvec(Pb + 6 * 100, Ew);
#pragma unroll
            for (int i = 0; i < 10; ++i) Ew[i] += wt[j][i];
        }
        // note: E_w recurrence is E <- P6*E + wt[j]; with E starting 0 the first
        // matvec is a no-op, matching E_w = sum_j P6^(w-1-j) wt[j].
#pragma unroll
        for (int i = 0; i < 10; ++i) F[i] += Ew[i];
    }
#pragma unroll
    for (int m = 0; m < 6; ++m) {
        if ((lw >> m) & 1) matvec(Pb + m * 100, F);
    }
#pragma unroll
    for (int k = 0; k < 5; ++k) {
        z1[k] = F[2 * k]     + es[2 * k];
        z2[k] = F[2 * k + 1] + es[2 * k + 1];
    }

    // ---- final cascade from exact state -> y ----
    float* yp = y + (size_t)b * T_LEN + (size_t)c * LCH;
#pragma unroll
    for (int t0 = 0; t0 < LCH; t0 += 4) {
        float o4[4];
#pragma unroll
        for (int j = 0; j < 4; ++j) {
            float s = xr[t0 + j];
#pragma unroll
            for (int k = 0; k < 5; ++k) {
                float yk = fmaf(cb0[k], s, z1[k]);
                float u  = fmaf(cb1[k], s, z2[k]);
                z1[k] = fmaf(-ca1[k], yk, u);
                z2[k] = fmaf(-ca2[k], yk, cb2[k] * s);
                s = yk;
            }
            o4[j] = s;
        }
        *reinterpret_cast<float4*>(yp + t0) = make_float4(o4[0], o4[1], o4[2], o4[3]);
    }
}

extern "C" void kernel_launch(void* const* d_in, const int* in_sizes, int n_in,
                              void* d_out, int out_size, void* d_ws, size_t ws_size,
                              hipStream_t stream)
{
    const float* x  = (const float*)d_in[0];
    const float* cp = (const float*)d_in[1];
    float* out = (float*)d_out;
    float* sos = out + (size_t)NB * T_LEN;                 // sos tail of d_out

    float*        powers = (float*)d_ws;                   // NB*NPOW*100
    float*        agg    = powers + (size_t)NB * NPOW * 100;   // NB*16*10
    unsigned int* flags  = (unsigned int*)(agg + (size_t)NB * SPB * 10);  // NB*16

    eq_setup<<<dim3(NB), dim3(128), 0, stream>>>(cp, sos, powers, flags);
    eq_main<<<dim3(NB * SPB), dim3(256), 0, stream>>>(x, sos, powers, agg, flags, out);
}

// Round 5
// 49.189 us; speedup vs baseline: 3.9837x; 1.1816x over previous
//
#include <hip/hip_runtime.h>
#include <math.h>

// ParametricEQ: 5-section cascaded biquad over (32, 131072).
// Single 10-state linear recurrence z' = A z + b x, two launches:
//   K1 setup: RBJ coeffs (fp64) + P_m = A^(32*2^m) m=0..11; zero publish flags.
//   K2 main (512 blocks x 256 thr; block = 256 chunks x 32 samples):
//     powers -> LDS (padded 10x12 rows, float4 ds_reads, broadcast);
//     x->regs; zero-state cascade -> chunk states; in-wave KS (P_0..P_5, LDS-fed);
//     block aggregate via P_6; publish (agent-scope release);
//     wait 16 sibling flags; in-wave KS over aggregates (P_8..P_11);
//     per-thread reconstruction (P_6/P_7 wave step + conditional P_0..P_5);
//     final cascade -> y.  x read once from HBM; P-matrices never re-read
//     from global in the hot path.

#define NB 32
#define LCH 32
#define T_LEN 131072
#define CPB 256                 // chunks per block
#define SPB 16                  // blocks (spans) per batch
#define NPOW 12
#define PROW 12                 // padded row stride (floats) for LDS P

__constant__ double c_lo[15] = {-12.0,   20.0, 0.1,
                                -12.0,   20.0, 0.1,
                                -12.0,  200.0, 0.1,
                                -12.0, 2000.0, 0.1,
                                -12.0, 4000.0, 0.1};
__constant__ double c_hi[15] = { 12.0,  2000.0, 10.0,
                                 12.0,   200.0, 10.0,
                                 12.0,  2000.0, 10.0,
                                 12.0, 12000.0, 10.0,
                                 12.0, 16000.0, 10.0};

// ---------------- K1: coeffs + cascade matrix powers + flag clear -----------
__global__ __launch_bounds__(128)
void eq_setup(const float* __restrict__ cp, float* __restrict__ sos_out,
              float* __restrict__ powers, unsigned int* __restrict__ flags)
{
    int b = blockIdx.x;
    int t = threadIdx.x;
    __shared__ float  sc[5][5];
    __shared__ double Abuf[2][10][10];

    if (t < SPB) flags[b * SPB + t] = 0u;   // clear publish flags (pre-main)

    if (t < 5) {
        int k = t;
        double p[3];
#pragma unroll
        for (int j = 0; j < 3; ++j) {
            int i = k * 3 + j;
            double pv = (double)cp[b * 15 + i];
            p[j] = c_lo[i] + pv * (c_hi[i] - c_lo[i]);
        }
        double A     = exp(p[0] * (M_LN10 / 40.0));
        double w0    = 2.0 * M_PI * p[1] / 44100.0;
        double alpha = sin(w0) / (2.0 * p[2]);
        double cw    = cos(w0);
        double sA    = sqrt(A);
        double b0, b1, b2, a0, a1, a2;
        if (k == 0) {            // low shelf
            b0 =     A * ((A + 1) - (A - 1) * cw + 2 * sA * alpha);
            b1 = 2 * A * ((A - 1) - (A + 1) * cw);
            b2 =     A * ((A + 1) - (A - 1) * cw - 2 * sA * alpha);
            a0 =          (A + 1) + (A - 1) * cw + 2 * sA * alpha;
            a1 =    -2 * ((A - 1) + (A + 1) * cw);
            a2 =          (A + 1) + (A - 1) * cw - 2 * sA * alpha;
        } else if (k == 4) {     // high shelf
            b0 =     A * ((A + 1) + (A - 1) * cw + 2 * sA * alpha);
            b1 = -2 * A * ((A - 1) + (A + 1) * cw);
            b2 =     A * ((A + 1) + (A - 1) * cw - 2 * sA * alpha);
            a0 =          (A + 1) - (A - 1) * cw + 2 * sA * alpha;
            a1 =     2 * ((A - 1) - (A + 1) * cw);
            a2 =          (A + 1) - (A - 1) * cw - 2 * sA * alpha;
        } else {                 // peaking
            b0 = 1.0 + alpha * A;
            b1 = -2.0 * cw;
            b2 = 1.0 - alpha * A;
            a0 = 1.0 + alpha / A;
            a1 = -2.0 * cw;
            a2 = 1.0 - alpha / A;
        }
        double inv = 1.0 / a0;
        float fb0 = (float)(b0 * inv), fb1 = (float)(b1 * inv), fb2 = (float)(b2 * inv);
        float fa1 = (float)(a1 * inv), fa2 = (float)(a2 * inv);
        float* o = sos_out + (size_t)(b * 5 + k) * 6;
        o[0] = fb0; o[1] = fb1; o[2] = fb2; o[3] = 1.0f; o[4] = fa1; o[5] = fa2;
        sc[k][0] = fb0; sc[k][1] = fb1; sc[k][2] = fb2; sc[k][3] = fa1; sc[k][4] = fa2;
    }
    __syncthreads();

    // A (10x10): column i = one-sample cascade update of basis e_i with x=0.
    if (t < 10) {
        double z[10];
#pragma unroll
        for (int i = 0; i < 10; ++i) z[i] = 0.0;
        z[t] = 1.0;
        double s = 0.0;
        double zn[10];
#pragma unroll
        for (int k = 0; k < 5; ++k) {
            double b0 = sc[k][0], b1 = sc[k][1], b2 = sc[k][2];
            double a1 = sc[k][3], a2 = sc[k][4];
            double y = b0 * s + z[2 * k];
            zn[2 * k]     = b1 * s - a1 * y + z[2 * k + 1];
            zn[2 * k + 1] = b2 * s - a2 * y;
            s = y;
        }
#pragma unroll
        for (int r = 0; r < 10; ++r) Abuf[0][r][t] = zn[r];
    }
    __syncthreads();

    int r = t / 10, cc = t % 10;
    int cur = 0;
    for (int sq = 0; sq < 16; ++sq) {
        double acc = 0.0;
        if (t < 100) {
#pragma unroll
            for (int j = 0; j < 10; ++j) acc += Abuf[cur][r][j] * Abuf[cur][j][cc];
        }
        __syncthreads();
        if (t < 100) Abuf[cur ^ 1][r][cc] = acc;
        __syncthreads();
        cur ^= 1;
        if (sq >= 4 && t < 100) {
            int m = sq - 4;   // sq=4 -> A^32 = P_0
            powers[((size_t)b * NPOW + m) * 100 + t] = (float)Abuf[cur][r][cc];
        }
    }
}

// ---- v = P*u (+ v if ACC), P = LDS 10x12 padded rows, u[10..11]==0 ----------
template<bool ACC>
__device__ __forceinline__ void affineL(const float* __restrict__ P,
                                        const float u[PROW], float v[10])
{
#pragma unroll
    for (int rr = 0; rr < 10; ++rr) {
        const float* rp = P + rr * PROW;
        float a = ACC ? v[rr] : 0.0f;
#pragma unroll
        for (int c = 0; c < PROW; ++c) a = fmaf(rp[c], u[c], a);
        v[rr] = a;
    }
}

__device__ __forceinline__ void matvecL(const float* __restrict__ P, float v[10])
{
    float u[PROW];
#pragma unroll
    for (int i = 0; i < 10; ++i) u[i] = v[i];
    u[10] = 0.0f; u[11] = 0.0f;
    affineL<false>(P, u, v);
}

// ---------------- K2: main ----------------
__global__ __launch_bounds__(256, 2)
void eq_main(const float* __restrict__ x, const float* __restrict__ sos,
             const float* __restrict__ powers, float* __restrict__ agg,
             unsigned int* __restrict__ flags, float* __restrict__ y)
{
    int blk = blockIdx.x;
    int b = blk >> 4, sp = blk & (SPB - 1);
    int tid = threadIdx.x;
    int w = tid >> 6, lw = tid & 63;

    __shared__ float Pl[NPOW * 10 * PROW];   // padded P matrices (5.76 KB)
    __shared__ float wt[4][10];
    __shared__ float Sseed[10];

    // ---- stage P matrices into LDS (pad cols 10,11 with 0) ----
    {
        const float* src = powers + (size_t)b * NPOW * 100;
        for (int i = tid; i < NPOW * 10 * PROW; i += 256) {
            int c = i % PROW;
            int r = (i / PROW) % 10;
            int m = i / (10 * PROW);
            Pl[i] = (c < 10) ? src[m * 100 + r * 10 + c] : 0.0f;
        }
    }

    const float* s5 = sos + (size_t)(b * 5) * 6;
    float cb0[5], cb1[5], cb2[5], ca1[5], ca2[5];
#pragma unroll
    for (int k = 0; k < 5; ++k) {
        cb0[k] = s5[k * 6 + 0]; cb1[k] = s5[k * 6 + 1]; cb2[k] = s5[k * 6 + 2];
        ca1[k] = s5[k * 6 + 4]; ca2[k] = s5[k * 6 + 5];
    }

    // ---- load 32 samples to registers ----
    int c = sp * CPB + tid;                       // chunk index in batch
    const float* xp = x + (size_t)b * T_LEN + (size_t)c * LCH;
    float xr[LCH];
#pragma unroll
    for (int t0 = 0; t0 < LCH; t0 += 4) {
        float4 xv = *reinterpret_cast<const float4*>(xp + t0);
        xr[t0] = xv.x; xr[t0 + 1] = xv.y; xr[t0 + 2] = xv.z; xr[t0 + 3] = xv.w;
    }

    // ---- zero-state cascade -> chunk end state ----
    float z1[5] = {0, 0, 0, 0, 0}, z2[5] = {0, 0, 0, 0, 0};
#pragma unroll
    for (int j = 0; j < LCH; ++j) {
        float s = xr[j];
#pragma unroll
        for (int k = 0; k < 5; ++k) {
            float yk = fmaf(cb0[k], s, z1[k]);
            float u  = fmaf(cb1[k], s, z2[k]);
            z1[k] = fmaf(-ca1[k], yk, u);
            z2[k] = fmaf(-ca2[k], yk, cb2[k] * s);
            s = yk;
        }
    }
    float sv[10];
#pragma unroll
    for (int k = 0; k < 5; ++k) { sv[2 * k] = z1[k]; sv[2 * k + 1] = z2[k]; }

    __syncthreads();   // Pl staged

    // ---- in-wave KS scan over 64 chunks (P_0..P_5 from LDS) ----
#pragma unroll
    for (int j = 0; j < 6; ++j) {
        const float* P = Pl + j * 10 * PROW;
        float u[PROW];
#pragma unroll
        for (int i = 0; i < 10; ++i) u[i] = __shfl_up(sv[i], 1 << j);
        u[10] = 0.0f; u[11] = 0.0f;
        if (lw >= (1 << j)) affineL<true>(P, u, sv);
    }
    // exclusive in-wave prefix
    float es[10];
#pragma unroll
    for (int i = 0; i < 10; ++i) es[i] = __shfl_up(sv[i], 1);
    if (lw == 0) {
#pragma unroll
        for (int i = 0; i < 10; ++i) es[i] = 0.0f;
    }
    if (lw == 63) {
#pragma unroll
        for (int i = 0; i < 10; ++i) wt[w][i] = sv[i];
    }
    __syncthreads();

    // ---- block aggregate (thread 0): E = P6*E + wt[j], publish ----
    if (tid == 0) {
        float E[10];
#pragma unroll
        for (int i = 0; i < 10; ++i) E[i] = wt[0][i];
#pragma unroll
        for (int j = 1; j < 4; ++j) {
            matvecL(Pl + 6 * 10 * PROW, E);
#pragma unroll
            for (int i = 0; i < 10; ++i) E[i] += wt[j][i];
        }
        float* ap = agg + (size_t)(b * SPB + sp) * 10;
#pragma unroll
        for (int i = 0; i < 10; ++i)
            __hip_atomic_store(&ap[i], E[i], __ATOMIC_RELAXED, __HIP_MEMORY_SCOPE_AGENT);
        __hip_atomic_store(&flags[b * SPB + sp], 1u, __ATOMIC_RELEASE,
                           __HIP_MEMORY_SCOPE_AGENT);
    }

    // ---- wave 0: wait 16 sibling aggregates, KS over 16 (P_8..P_11) ----
    if (w == 0) {
        float tv[10];
#pragma unroll
        for (int i = 0; i < 10; ++i) tv[i] = 0.0f;
        if (lw < SPB) {
            while (__hip_atomic_load(&flags[b * SPB + lw], __ATOMIC_ACQUIRE,
                                     __HIP_MEMORY_SCOPE_AGENT) == 0u) {
                __builtin_amdgcn_s_sleep(1);
            }
            const float* ap = agg + (size_t)(b * SPB + lw) * 10;
#pragma unroll
            for (int i = 0; i < 10; ++i)
                tv[i] = __hip_atomic_load(&ap[i], __ATOMIC_RELAXED,
                                          __HIP_MEMORY_SCOPE_AGENT);
        }
#pragma unroll
        for (int j = 0; j < 4; ++j) {
            const float* P = Pl + (8 + j) * 10 * PROW;
            float u[PROW];
#pragma unroll
            for (int i = 0; i < 10; ++i) u[i] = __shfl_up(tv[i], 1 << j);
            u[10] = 0.0f; u[11] = 0.0f;
            if (lw >= (1 << j) && lw < SPB) affineL<true>(P, u, tv);
        }
        float sd[10];
#pragma unroll
        for (int i = 0; i < 10; ++i) sd[i] = __shfl(tv[i], (sp - 1) & 63);
        if (sp == 0) {
#pragma unroll
            for (int i = 0; i < 10; ++i) sd[i] = 0.0f;
        }
        if (lw == 0) {
#pragma unroll
            for (int i = 0; i < 10; ++i) Sseed[i] = sd[i];
        }
    }
    __syncthreads();

    // ---- exact entering state for this chunk ----
    float F[10];
#pragma unroll
    for (int i = 0; i < 10; ++i) F[i] = Sseed[i];
    if (w & 1) matvecL(Pl + 6 * 10 * PROW, F);   // A^2048
    if (w & 2) matvecL(Pl + 7 * 10 * PROW, F);   // A^4096
    {
        float Ew[10];
#pragma unroll
        for (int i = 0; i < 10; ++i) Ew[i] = 0.0f;
        for (int j = 0; j < w; ++j) {
            matvecL(Pl + 6 * 10 * PROW, Ew);
#pragma unroll
            for (int i = 0; i < 10; ++i) Ew[i] += wt[j][i];
        }
#pragma unroll
        for (int i = 0; i < 10; ++i) F[i] += Ew[i];
    }
#pragma unroll
    for (int m = 0; m < 6; ++m) {
        if ((lw >> m) & 1) matvecL(Pl + m * 10 * PROW, F);
    }
#pragma unroll
    for (int k = 0; k < 5; ++k) {
        z1[k] = F[2 * k]     + es[2 * k];
        z2[k] = F[2 * k + 1] + es[2 * k + 1];
    }

    // ---- final cascade from exact state -> y ----
    float* yp = y + (size_t)b * T_LEN + (size_t)c * LCH;
#pragma unroll
    for (int t0 = 0; t0 < LCH; t0 += 4) {
        float o4[4];
#pragma unroll
        for (int j = 0; j < 4; ++j) {
            float s = xr[t0 + j];
#pragma unroll
            for (int k = 0; k < 5; ++k) {
                float yk = fmaf(cb0[k], s, z1[k]);
                float u  = fmaf(cb1[k], s, z2[k]);
                z1[k] = fmaf(-ca1[k], yk, u);
                z2[k] = fmaf(-ca2[k], yk, cb2[k] * s);
                s = yk;
            }
            o4[j] = s;
        }
        *reinterpret_cast<float4*>(yp + t0) = make_float4(o4[0], o4[1], o4[2], o4[3]);
    }
}

extern "C" void kernel_launch(void* const* d_in, const int* in_sizes, int n_in,
                              void* d_out, int out_size, void* d_ws, size_t ws_size,
                              hipStream_t stream)
{
    const float* x  = (const float*)d_in[0];
    const float* cp = (const float*)d_in[1];
    float* out = (float*)d_out;
    float* sos = out + (size_t)NB * T_LEN;                 // sos tail of d_out

    float*        powers = (float*)d_ws;                   // NB*NPOW*100
    float*        agg    = powers + (size_t)NB * NPOW * 100;   // NB*16*10
    unsigned int* flags  = (unsigned int*)(agg + (size_t)NB * SPB * 10);  // NB*16

    eq_setup<<<dim3(NB), dim3(128), 0, stream>>>(cp, sos, powers, flags);
    eq_main<<<dim3(NB * SPB), dim3(256), 0, stream>>>(x, sos, powers, agg, flags, out);
}